// Round 22
// baseline (83.873 us; speedup 1.0000x reference)
//
#include <hip/hip_runtime.h>

#define N_NODES   100000
#define N_EDGES   600000
#define D_FEAT    128
#define N_CLASSES 40
#define USTRIDE   64                // bf16 elems/row -> 128 B, one cache line
#define MAXW      40                // ELL width; P(Poisson(6) > 40) ~ 1e-24, guarded

#define NPAD      100352            // N_NODES padded to 1024 multiple
#define N_TILES   (N_NODES / 16)    // 6250 exact
#define G_GEMM    ((N_TILES + 3) / 4)            // 1563 gemm blocks (4 waves/blk)
#define EPB       384                             // edges per block (1563*384 >= 600k)
#define G_ZERO    (NPAD / 4 / 256 + 1)           // 98 zero blocks + 1 wconv block

typedef __attribute__((ext_vector_type(8))) short bf16x8;
typedef __attribute__((ext_vector_type(4))) float f32x4;

// ---------- bf16 helpers (RTNE) ----------
__device__ __forceinline__ float bf2f(unsigned int h) { return __uint_as_float(h << 16); }
__device__ __forceinline__ unsigned int f2bf(float f) {
    unsigned int u = __float_as_uint(f);
    return (u + 0x7FFFu + ((u >> 16) & 1u)) >> 16;
}
__device__ __forceinline__ float4 up4(uint2 v) {
    return make_float4(bf2f(v.x & 0xFFFFu), bf2f(v.x >> 16),
                       bf2f(v.y & 0xFFFFu), bf2f(v.y >> 16));
}
__device__ __forceinline__ uint2 pk4(float4 f) {
    uint2 r;
    r.x = f2bf(f.x) | (f2bf(f.y) << 16);
    r.y = f2bf(f.z) | (f2bf(f.w) << 16);
    return r;
}

// ================= zero deg + precompute W MFMA fragments =================

__global__ void k_zero_wconv(int4* __restrict__ deg4, const float* __restrict__ W,
                             uint4* __restrict__ wfrag) {
    int t = threadIdx.x;
    if (blockIdx.x < G_ZERO - 1) {
        int i = blockIdx.x * 256 + t;
        if (i < NPAD / 4) deg4[i] = make_int4(0, 0, 0, 0);
        return;
    }
    for (int idx = t; idx < 768; idx += 256) {
        int lane = idx & 63;
        int kc   = (idx >> 6) & 3;
        int ct   = idx >> 8;
        int r16  = lane & 15;
        int g    = lane >> 4;
        int j    = ct * 16 + r16;
        uint4 o = make_uint4(0u, 0u, 0u, 0u);
        if (j < N_CLASSES) {
            const float* wr = W + (size_t)j * D_FEAT + kc * 32 + g * 8;
            float4 w0 = *(const float4*)wr;
            float4 w1 = *(const float4*)(wr + 4);
            o.x = f2bf(w0.x) | (f2bf(w0.y) << 16);
            o.y = f2bf(w0.z) | (f2bf(w0.w) << 16);
            o.z = f2bf(w1.x) | (f2bf(w1.y) << 16);
            o.w = f2bf(w1.z) | (f2bf(w1.w) << 16);
        }
        wfrag[idx] = o;
    }
}

// ========== fused: MFMA gemm + count + ELL fill (software-pipelined) ==========
// ELL is TRANSPOSED: ell[o * N_NODES + d]. Poisson(6) degrees put ~all
// writes in ~12 L2-resident 400KB planes with ~97% line coverage -> L2
// write-combining replaces the per-edge 128B RMW (r21: 48.8 MB WRITE for
// 15.6 MB logical) with clean writeback. Gather reads become coalesced.

__global__ __launch_bounds__(256) void k_gemm_ell(const float* __restrict__ x,
                                                  const uint4* __restrict__ wfrag,
                                                  unsigned short* __restrict__ y0,
                                                  const int* __restrict__ esrc,
                                                  const int* __restrict__ edst,
                                                  int* __restrict__ deg,
                                                  int* __restrict__ ell) {
    int t = threadIdx.x;
    int wid = t >> 6;
    int lane = t & 63;
    int tile = blockIdx.x * 4 + wid;
    bool valid = tile < N_TILES;

    int r16 = lane & 15;           // node-in-tile (B-operand col / D col)
    int g   = lane >> 4;           // k-group (8 elems each)
    int node = tile * 16 + r16;

    // --- stage 1: edge loads (2 slots/thread, EPB=384) ---
    int e0 = blockIdx.x * EPB + t;
    int e1 = e0 + 256;
    bool v0 = e0 < N_EDGES;
    bool v1 = (t < EPB - 256) && (e1 < N_EDGES);
    int d0 = 0, d1 = 0, src0 = 0, src1 = 0;
    if (v0) { d0 = edst[e0]; src0 = esrc[e0]; }
    if (v1) { d1 = edst[e1]; src1 = esrc[e1]; }

    // --- stage 2: gemm loads (12 wfrag + 8 x, b128 each) ---
    uint4 wq[12];
    float4 xv[8];
    if (valid) {
#pragma unroll
        for (int f = 0; f < 12; ++f) wq[f] = wfrag[f * 64 + lane];
        const float4* xp = (const float4*)(x + (size_t)node * D_FEAT);
#pragma unroll
        for (int kc = 0; kc < 4; ++kc) {
            xv[kc * 2]     = xp[kc * 8 + g * 2];
            xv[kc * 2 + 1] = xp[kc * 8 + g * 2 + 1];
        }
    }

    // --- stage 3: atomics issue (returns consumed only in stage 6) ---
    int o0 = 0, o1 = 0;
    if (v0) o0 = atomicAdd(&deg[d0], 1);
    if (v1) o1 = atomicAdd(&deg[d1], 1);

    // --- stage 4: convert x to bf16 fragments ---
    bf16x8 afrag[4];
    if (valid) {
#pragma unroll
        for (int kc = 0; kc < 4; ++kc) {
            union { bf16x8 v; unsigned int u[4]; } a;
            a.u[0] = f2bf(xv[kc * 2].x) | (f2bf(xv[kc * 2].y) << 16);
            a.u[1] = f2bf(xv[kc * 2].z) | (f2bf(xv[kc * 2].w) << 16);
            a.u[2] = f2bf(xv[kc * 2 + 1].x) | (f2bf(xv[kc * 2 + 1].y) << 16);
            a.u[3] = f2bf(xv[kc * 2 + 1].z) | (f2bf(xv[kc * 2 + 1].w) << 16);
            afrag[kc] = a.v;
        }
    }

    // --- stage 5: MFMA chain (atomic latency hides under this) ---
    f32x4 z = {0.f, 0.f, 0.f, 0.f};
    f32x4 acc0 = z, acc1 = z, acc2 = z;
    if (valid) {
#pragma unroll
        for (int kc = 0; kc < 4; ++kc) {
            union { uint4 u4; bf16x8 v; } b0, b1, b2;
            b0.u4 = wq[kc];  b1.u4 = wq[4 + kc];  b2.u4 = wq[8 + kc];
            acc0 = __builtin_amdgcn_mfma_f32_16x16x32_bf16(b0.v, afrag[kc], acc0, 0, 0, 0);
            acc1 = __builtin_amdgcn_mfma_f32_16x16x32_bf16(b1.v, afrag[kc], acc1, 0, 0, 0);
            acc2 = __builtin_amdgcn_mfma_f32_16x16x32_bf16(b2.v, afrag[kc], acc2, 0, 0, 0);
        }
    }

    // --- stage 6: ELL stores (transposed planes; first consumers of o0/o1) ---
    if (v0 && o0 < MAXW) ell[(size_t)o0 * N_NODES + d0] = src0;
    if (v1 && o1 < MAXW) ell[(size_t)o1 * N_NODES + d1] = src1;

    if (!valid) return;

    // --- epilogue: unscaled y0; full-line coverage via pad-zero stores ---
    unsigned short* orow = y0 + (size_t)node * USTRIDE;
    uint2 s0, s1;
    s0.x = f2bf(acc0[0]) | (f2bf(acc0[1]) << 16);
    s0.y = f2bf(acc0[2]) | (f2bf(acc0[3]) << 16);
    *(uint2*)(orow + g * 4) = s0;
    s1.x = f2bf(acc1[0]) | (f2bf(acc1[1]) << 16);
    s1.y = f2bf(acc1[2]) | (f2bf(acc1[3]) << 16);
    *(uint2*)(orow + 16 + g * 4) = s1;
    if (g < 2) {
        uint2 s2;
        s2.x = f2bf(acc2[0]) | (f2bf(acc2[1]) << 16);
        s2.y = f2bf(acc2[2]) | (f2bf(acc2[3]) << 16);
        *(uint2*)(orow + 32 + g * 4) = s2;
    } else {
        *(uint4*)(orow + 32 + g * 8) = make_uint4(0u, 0u, 0u, 0u);  // shorts 48..63
    }
    if (g == 1) *(uint4*)(orow + 40) = make_uint4(0u, 0u, 0u, 0u);  // shorts 40..47
}

// ================= round 1: u1[d] = dinv_d^2 * (dinv_d*y0[d] + sum dinv_s*y0[s]) =====
// ell[par*N + i] with consecutive i across the block -> coalesced reads.

__global__ __launch_bounds__(256) void k_gather1(const unsigned short* __restrict__ y0,
                                                 unsigned short* __restrict__ u1,
                                                 const int* __restrict__ deg,
                                                 const int* __restrict__ ell) {
    int t = blockIdx.x * blockDim.x + threadIdx.x;
    int i = t >> 4;
    if (i >= N_NODES) return;
    int sub = t & 1;
    int par = (t >> 1) & 7;
    const uint2* yb = (const uint2*)y0;

    int degi = deg[i];
    float di = rsqrtf((float)(degi + 1));

    float4 a[5];
    if (par == 0) {
        const uint2* self = yb + (size_t)i * 16 + sub * 5;
#pragma unroll
        for (int r = 0; r < 5; ++r) {
            float4 v = up4(self[r]);
            a[r] = make_float4(v.x * di, v.y * di, v.z * di, v.w * di);
        }
    } else {
#pragma unroll
        for (int r = 0; r < 5; ++r) a[r] = make_float4(0.f, 0.f, 0.f, 0.f);
    }

    int nd = degi < MAXW ? degi : MAXW;
    for (int k = par; k < nd; k += 8) {
        int s = ell[(size_t)k * N_NODES + i];
        float ds = rsqrtf((float)(deg[s] + 1));
        const uint2* p = yb + (size_t)s * 16 + sub * 5;
        uint2 w[5];
#pragma unroll
        for (int r = 0; r < 5; ++r) w[r] = p[r];
#pragma unroll
        for (int r = 0; r < 5; ++r) {
            float4 v = up4(w[r]);
            a[r].x += v.x * ds; a[r].y += v.y * ds;
            a[r].z += v.z * ds; a[r].w += v.w * ds;
        }
    }

#pragma unroll
    for (int d = 2; d <= 8; d <<= 1) {
#pragma unroll
        for (int r = 0; r < 5; ++r) {
            a[r].x += __shfl_xor(a[r].x, d); a[r].y += __shfl_xor(a[r].y, d);
            a[r].z += __shfl_xor(a[r].z, d); a[r].w += __shfl_xor(a[r].w, d);
        }
    }

    unsigned short* orow = u1 + (size_t)i * USTRIDE;
    if (par == 0) {
        float s2 = di * di;
        uint2* o = (uint2*)orow + sub * 5;
#pragma unroll
        for (int r = 0; r < 5; ++r) {
            o[r] = pk4(make_float4(a[r].x * s2, a[r].y * s2, a[r].z * s2, a[r].w * s2));
        }
    } else if (par == 1) {
        *(uint4*)(orow + 40 + sub * 8) = make_uint4(0u, 0u, 0u, 0u);  // shorts 40..55
    } else if (par == 2 && sub == 0) {
        *(uint4*)(orow + 56) = make_uint4(0u, 0u, 0u, 0u);            // shorts 56..63
    }
}

// ======= round 2 + head: logits = dinv_d*(u1[d] + sum u1[s]) + b, log_softmax =======

__global__ __launch_bounds__(256) void k_gather_out(const unsigned short* __restrict__ u1,
                                                    float* __restrict__ out,
                                                    const int* __restrict__ deg,
                                                    const int* __restrict__ ell,
                                                    const float* __restrict__ bias) {
    int t = blockIdx.x * blockDim.x + threadIdx.x;
    int i = t >> 4;
    if (i >= N_NODES) return;
    int sub = t & 1;
    int par = (t >> 1) & 7;
    const uint2* yb = (const uint2*)u1;

    int degi = deg[i];
    float di = rsqrtf((float)(degi + 1));

    float4 a[5];
    if (par == 0) {
        const uint2* self = yb + (size_t)i * 16 + sub * 5;
#pragma unroll
        for (int r = 0; r < 5; ++r) a[r] = up4(self[r]);
    } else {
#pragma unroll
        for (int r = 0; r < 5; ++r) a[r] = make_float4(0.f, 0.f, 0.f, 0.f);
    }

    int nd = degi < MAXW ? degi : MAXW;
    for (int k = par; k < nd; k += 8) {
        int s = ell[(size_t)k * N_NODES + i];
        const uint2* p = yb + (size_t)s * 16 + sub * 5;
        uint2 w[5];
#pragma unroll
        for (int r = 0; r < 5; ++r) w[r] = p[r];
#pragma unroll
        for (int r = 0; r < 5; ++r) {
            float4 v = up4(w[r]);
            a[r].x += v.x; a[r].y += v.y; a[r].z += v.z; a[r].w += v.w;
        }
    }

#pragma unroll
    for (int d = 2; d <= 8; d <<= 1) {
#pragma unroll
        for (int r = 0; r < 5; ++r) {
            a[r].x += __shfl_xor(a[r].x, d); a[r].y += __shfl_xor(a[r].y, d);
            a[r].z += __shfl_xor(a[r].z, d); a[r].w += __shfl_xor(a[r].w, d);
        }
    }

    const float4* b4 = (const float4*)bias + sub * 5;
    float4 l[5];
    float m = -INFINITY;
#pragma unroll
    for (int r = 0; r < 5; ++r) {
        float4 b = b4[r];
        l[r].x = a[r].x * di + b.x;
        l[r].y = a[r].y * di + b.y;
        l[r].z = a[r].z * di + b.z;
        l[r].w = a[r].w * di + b.w;
        m = fmaxf(m, fmaxf(fmaxf(l[r].x, l[r].y), fmaxf(l[r].z, l[r].w)));
    }
    m = fmaxf(m, __shfl_xor(m, 1));     // combine class halves (bit 0)
    float s = 0.f;
#pragma unroll
    for (int r = 0; r < 5; ++r) {
        s += __expf(l[r].x - m) + __expf(l[r].y - m)
           + __expf(l[r].z - m) + __expf(l[r].w - m);
    }
    s += __shfl_xor(s, 1);
    float lse = __logf(s) + m;

    if (par == 0) {
        float4* o = (float4*)out + (size_t)i * 10 + sub * 5;
#pragma unroll
        for (int r = 0; r < 5; ++r) {
            o[r] = make_float4(l[r].x - lse, l[r].y - lse, l[r].z - lse, l[r].w - lse);
        }
    }
}

// ================= launch =================

extern "C" void kernel_launch(void* const* d_in, const int* in_sizes, int n_in,
                              void* d_out, int out_size, void* d_ws, size_t ws_size,
                              hipStream_t stream) {
    const float* x   = (const float*)d_in[0];
    const int*   ei  = (const int*)d_in[1];
    const float* W   = (const float*)d_in[2];
    const float* b   = (const float*)d_in[3];
    float*       out = (float*)d_out;

    const int* esrc = ei;
    const int* edst = ei + N_EDGES;

    // workspace layout
    int*   deg   = (int*)d_ws;                         // NPAD ints
    uint4* wfrag = (uint4*)(deg + NPAD);               // 768 uint4 (3072 ints)
    int*   ell   = (int*)(deg + NPAD + 3072);          // MAXW planes x N_NODES ints
    unsigned short* y0 = (unsigned short*)(ell + (size_t)N_NODES * MAXW); // 6.4M shorts
    unsigned short* u1 = y0 + (size_t)N_NODES * USTRIDE;

    const int B = 256;
    const int gG = (16 * N_NODES + B - 1) / B;         // 6250 (16 threads/node)

    k_zero_wconv<<<G_ZERO, B, 0, stream>>>((int4*)deg, W, wfrag);
    k_gemm_ell<<<G_GEMM, B, 0, stream>>>(x, wfrag, y0, esrc, edst, deg, ell);
    k_gather1  <<<gG, B, 0, stream>>>(y0, u1, deg, ell);
    k_gather_out<<<gG, B, 0, stream>>>(u1, out, deg, ell, b);
}

// Round 23
// 83.632 us; speedup vs baseline: 1.0029x; 1.0029x over previous
//
#include <hip/hip_runtime.h>

#define N_NODES   100000
#define N_EDGES   600000
#define D_FEAT    128
#define N_CLASSES 40
#define USTRIDE   64                // bf16 elems/row -> 128 B, one cache line
#define MAXW      40                // ELL width; P(Poisson(6) > 40) ~ 1e-24, guarded

#define NPAD      100352            // N_NODES padded to 1024 multiple
#define N_TILES   (N_NODES / 16)    // 6250 exact
#define G_GEMM    1568                            // 196*8: XCD-swizzled tile map covers 6272 slots
#define EPB       384                             // edges per block (1568*384 >= 600k)
#define G_ZERO    (NPAD / 4 / 256 + 1)           // 98 zero blocks + 1 wconv block

typedef __attribute__((ext_vector_type(8))) short bf16x8;
typedef __attribute__((ext_vector_type(4))) float f32x4;

// ---------- bf16 helpers (RTNE) ----------
__device__ __forceinline__ float bf2f(unsigned int h) { return __uint_as_float(h << 16); }
__device__ __forceinline__ unsigned int f2bf(float f) {
    unsigned int u = __float_as_uint(f);
    return (u + 0x7FFFu + ((u >> 16) & 1u)) >> 16;
}
__device__ __forceinline__ float4 up4(uint2 v) {
    return make_float4(bf2f(v.x & 0xFFFFu), bf2f(v.x >> 16),
                       bf2f(v.y & 0xFFFFu), bf2f(v.y >> 16));
}
__device__ __forceinline__ uint2 pk4(float4 f) {
    uint2 r;
    r.x = f2bf(f.x) | (f2bf(f.y) << 16);
    r.y = f2bf(f.z) | (f2bf(f.w) << 16);
    return r;
}

// ================= zero deg + precompute W MFMA fragments =================

__global__ void k_zero_wconv(int4* __restrict__ deg4, const float* __restrict__ W,
                             uint4* __restrict__ wfrag) {
    int t = threadIdx.x;
    if (blockIdx.x < G_ZERO - 1) {
        int i = blockIdx.x * 256 + t;
        if (i < NPAD / 4) deg4[i] = make_int4(0, 0, 0, 0);
        return;
    }
    for (int idx = t; idx < 768; idx += 256) {
        int lane = idx & 63;
        int kc   = (idx >> 6) & 3;
        int ct   = idx >> 8;
        int r16  = lane & 15;
        int g    = lane >> 4;
        int j    = ct * 16 + r16;
        uint4 o = make_uint4(0u, 0u, 0u, 0u);
        if (j < N_CLASSES) {
            const float* wr = W + (size_t)j * D_FEAT + kc * 32 + g * 8;
            float4 w0 = *(const float4*)wr;
            float4 w1 = *(const float4*)(wr + 4);
            o.x = f2bf(w0.x) | (f2bf(w0.y) << 16);
            o.y = f2bf(w0.z) | (f2bf(w0.w) << 16);
            o.z = f2bf(w1.x) | (f2bf(w1.y) << 16);
            o.w = f2bf(w1.z) | (f2bf(w1.w) << 16);
        }
        wfrag[idx] = o;
    }
}

// ========== fused: MFMA gemm + count + ELL fill (software-pipelined) ==========
// XCD-locality swizzle: tile = (bid&7) + 8*((bid>>3)*4 + wid), so the block
// computing tile tau runs on XCD tau%8 — the SAME XCD as gather1's block
// g=tau that reads y0[tau] (gather grid: block g -> XCD g%8). The y0
// self-row link becomes L2-local instead of a 7/8 cross-XCD HBM miss.
// ELL stays transposed: ell[o * N_NODES + d].

__global__ __launch_bounds__(256) void k_gemm_ell(const float* __restrict__ x,
                                                  const uint4* __restrict__ wfrag,
                                                  unsigned short* __restrict__ y0,
                                                  const int* __restrict__ esrc,
                                                  const int* __restrict__ edst,
                                                  int* __restrict__ deg,
                                                  int* __restrict__ ell) {
    int t = threadIdx.x;
    int wid = t >> 6;
    int lane = t & 63;
    int tile = (blockIdx.x & 7) + 8 * ((blockIdx.x >> 3) * 4 + wid);
    bool valid = tile < N_TILES;

    int r16 = lane & 15;           // node-in-tile (B-operand col / D col)
    int g   = lane >> 4;           // k-group (8 elems each)
    int node = tile * 16 + r16;

    // --- stage 1: edge loads (2 slots/thread, EPB=384) ---
    int e0 = blockIdx.x * EPB + t;
    int e1 = e0 + 256;
    bool v0 = e0 < N_EDGES;
    bool v1 = (t < EPB - 256) && (e1 < N_EDGES);
    int d0 = 0, d1 = 0, src0 = 0, src1 = 0;
    if (v0) { d0 = edst[e0]; src0 = esrc[e0]; }
    if (v1) { d1 = edst[e1]; src1 = esrc[e1]; }

    // --- stage 2: gemm loads (12 wfrag + 8 x, b128 each) ---
    uint4 wq[12];
    float4 xv[8];
    if (valid) {
#pragma unroll
        for (int f = 0; f < 12; ++f) wq[f] = wfrag[f * 64 + lane];
        const float4* xp = (const float4*)(x + (size_t)node * D_FEAT);
#pragma unroll
        for (int kc = 0; kc < 4; ++kc) {
            xv[kc * 2]     = xp[kc * 8 + g * 2];
            xv[kc * 2 + 1] = xp[kc * 8 + g * 2 + 1];
        }
    }

    // --- stage 3: atomics issue (returns consumed only in stage 6) ---
    int o0 = 0, o1 = 0;
    if (v0) o0 = atomicAdd(&deg[d0], 1);
    if (v1) o1 = atomicAdd(&deg[d1], 1);

    // --- stage 4: convert x to bf16 fragments ---
    bf16x8 afrag[4];
    if (valid) {
#pragma unroll
        for (int kc = 0; kc < 4; ++kc) {
            union { bf16x8 v; unsigned int u[4]; } a;
            a.u[0] = f2bf(xv[kc * 2].x) | (f2bf(xv[kc * 2].y) << 16);
            a.u[1] = f2bf(xv[kc * 2].z) | (f2bf(xv[kc * 2].w) << 16);
            a.u[2] = f2bf(xv[kc * 2 + 1].x) | (f2bf(xv[kc * 2 + 1].y) << 16);
            a.u[3] = f2bf(xv[kc * 2 + 1].z) | (f2bf(xv[kc * 2 + 1].w) << 16);
            afrag[kc] = a.v;
        }
    }

    // --- stage 5: MFMA chain (atomic latency hides under this) ---
    f32x4 z = {0.f, 0.f, 0.f, 0.f};
    f32x4 acc0 = z, acc1 = z, acc2 = z;
    if (valid) {
#pragma unroll
        for (int kc = 0; kc < 4; ++kc) {
            union { uint4 u4; bf16x8 v; } b0, b1, b2;
            b0.u4 = wq[kc];  b1.u4 = wq[4 + kc];  b2.u4 = wq[8 + kc];
            acc0 = __builtin_amdgcn_mfma_f32_16x16x32_bf16(b0.v, afrag[kc], acc0, 0, 0, 0);
            acc1 = __builtin_amdgcn_mfma_f32_16x16x32_bf16(b1.v, afrag[kc], acc1, 0, 0, 0);
            acc2 = __builtin_amdgcn_mfma_f32_16x16x32_bf16(b2.v, afrag[kc], acc2, 0, 0, 0);
        }
    }

    // --- stage 6: ELL stores (transposed planes; first consumers of o0/o1) ---
    if (v0 && o0 < MAXW) ell[(size_t)o0 * N_NODES + d0] = src0;
    if (v1 && o1 < MAXW) ell[(size_t)o1 * N_NODES + d1] = src1;

    if (!valid) return;

    // --- epilogue: unscaled y0; full-line coverage via pad-zero stores ---
    unsigned short* orow = y0 + (size_t)node * USTRIDE;
    uint2 s0, s1;
    s0.x = f2bf(acc0[0]) | (f2bf(acc0[1]) << 16);
    s0.y = f2bf(acc0[2]) | (f2bf(acc0[3]) << 16);
    *(uint2*)(orow + g * 4) = s0;
    s1.x = f2bf(acc1[0]) | (f2bf(acc1[1]) << 16);
    s1.y = f2bf(acc1[2]) | (f2bf(acc1[3]) << 16);
    *(uint2*)(orow + 16 + g * 4) = s1;
    if (g < 2) {
        uint2 s2;
        s2.x = f2bf(acc2[0]) | (f2bf(acc2[1]) << 16);
        s2.y = f2bf(acc2[2]) | (f2bf(acc2[3]) << 16);
        *(uint2*)(orow + 32 + g * 4) = s2;
    } else {
        *(uint4*)(orow + 32 + g * 8) = make_uint4(0u, 0u, 0u, 0u);  // shorts 48..63
    }
    if (g == 1) *(uint4*)(orow + 40) = make_uint4(0u, 0u, 0u, 0u);  // shorts 40..47
}

// ================= round 1: u1[d] = dinv_d^2 * (dinv_d*y0[d] + sum dinv_s*y0[s]) =====
// ell[par*N + i] with consecutive i across the block -> coalesced reads.

__global__ __launch_bounds__(256) void k_gather1(const unsigned short* __restrict__ y0,
                                                 unsigned short* __restrict__ u1,
                                                 const int* __restrict__ deg,
                                                 const int* __restrict__ ell) {
    int t = blockIdx.x * blockDim.x + threadIdx.x;
    int i = t >> 4;
    if (i >= N_NODES) return;
    int sub = t & 1;
    int par = (t >> 1) & 7;
    const uint2* yb = (const uint2*)y0;

    int degi = deg[i];
    float di = rsqrtf((float)(degi + 1));

    float4 a[5];
    if (par == 0) {
        const uint2* self = yb + (size_t)i * 16 + sub * 5;
#pragma unroll
        for (int r = 0; r < 5; ++r) {
            float4 v = up4(self[r]);
            a[r] = make_float4(v.x * di, v.y * di, v.z * di, v.w * di);
        }
    } else {
#pragma unroll
        for (int r = 0; r < 5; ++r) a[r] = make_float4(0.f, 0.f, 0.f, 0.f);
    }

    int nd = degi < MAXW ? degi : MAXW;
    for (int k = par; k < nd; k += 8) {
        int s = ell[(size_t)k * N_NODES + i];
        float ds = rsqrtf((float)(deg[s] + 1));
        const uint2* p = yb + (size_t)s * 16 + sub * 5;
        uint2 w[5];
#pragma unroll
        for (int r = 0; r < 5; ++r) w[r] = p[r];
#pragma unroll
        for (int r = 0; r < 5; ++r) {
            float4 v = up4(w[r]);
            a[r].x += v.x * ds; a[r].y += v.y * ds;
            a[r].z += v.z * ds; a[r].w += v.w * ds;
        }
    }

#pragma unroll
    for (int d = 2; d <= 8; d <<= 1) {
#pragma unroll
        for (int r = 0; r < 5; ++r) {
            a[r].x += __shfl_xor(a[r].x, d); a[r].y += __shfl_xor(a[r].y, d);
            a[r].z += __shfl_xor(a[r].z, d); a[r].w += __shfl_xor(a[r].w, d);
        }
    }

    unsigned short* orow = u1 + (size_t)i * USTRIDE;
    if (par == 0) {
        float s2 = di * di;
        uint2* o = (uint2*)orow + sub * 5;
#pragma unroll
        for (int r = 0; r < 5; ++r) {
            o[r] = pk4(make_float4(a[r].x * s2, a[r].y * s2, a[r].z * s2, a[r].w * s2));
        }
    } else if (par == 1) {
        *(uint4*)(orow + 40 + sub * 8) = make_uint4(0u, 0u, 0u, 0u);  // shorts 40..55
    } else if (par == 2 && sub == 0) {
        *(uint4*)(orow + 56) = make_uint4(0u, 0u, 0u, 0u);            // shorts 56..63
    }
}

// ======= round 2 + head: logits = dinv_d*(u1[d] + sum u1[s]) + b, log_softmax =======

__global__ __launch_bounds__(256) void k_gather_out(const unsigned short* __restrict__ u1,
                                                    float* __restrict__ out,
                                                    const int* __restrict__ deg,
                                                    const int* __restrict__ ell,
                                                    const float* __restrict__ bias) {
    int t = blockIdx.x * blockDim.x + threadIdx.x;
    int i = t >> 4;
    if (i >= N_NODES) return;
    int sub = t & 1;
    int par = (t >> 1) & 7;
    const uint2* yb = (const uint2*)u1;

    int degi = deg[i];
    float di = rsqrtf((float)(degi + 1));

    float4 a[5];
    if (par == 0) {
        const uint2* self = yb + (size_t)i * 16 + sub * 5;
#pragma unroll
        for (int r = 0; r < 5; ++r) a[r] = up4(self[r]);
    } else {
#pragma unroll
        for (int r = 0; r < 5; ++r) a[r] = make_float4(0.f, 0.f, 0.f, 0.f);
    }

    int nd = degi < MAXW ? degi : MAXW;
    for (int k = par; k < nd; k += 8) {
        int s = ell[(size_t)k * N_NODES + i];
        const uint2* p = yb + (size_t)s * 16 + sub * 5;
        uint2 w[5];
#pragma unroll
        for (int r = 0; r < 5; ++r) w[r] = p[r];
#pragma unroll
        for (int r = 0; r < 5; ++r) {
            float4 v = up4(w[r]);
            a[r].x += v.x; a[r].y += v.y; a[r].z += v.z; a[r].w += v.w;
        }
    }

#pragma unroll
    for (int d = 2; d <= 8; d <<= 1) {
#pragma unroll
        for (int r = 0; r < 5; ++r) {
            a[r].x += __shfl_xor(a[r].x, d); a[r].y += __shfl_xor(a[r].y, d);
            a[r].z += __shfl_xor(a[r].z, d); a[r].w += __shfl_xor(a[r].w, d);
        }
    }

    const float4* b4 = (const float4*)bias + sub * 5;
    float4 l[5];
    float m = -INFINITY;
#pragma unroll
    for (int r = 0; r < 5; ++r) {
        float4 b = b4[r];
        l[r].x = a[r].x * di + b.x;
        l[r].y = a[r].y * di + b.y;
        l[r].z = a[r].z * di + b.z;
        l[r].w = a[r].w * di + b.w;
        m = fmaxf(m, fmaxf(fmaxf(l[r].x, l[r].y), fmaxf(l[r].z, l[r].w)));
    }
    m = fmaxf(m, __shfl_xor(m, 1));     // combine class halves (bit 0)
    float s = 0.f;
#pragma unroll
    for (int r = 0; r < 5; ++r) {
        s += __expf(l[r].x - m) + __expf(l[r].y - m)
           + __expf(l[r].z - m) + __expf(l[r].w - m);
    }
    s += __shfl_xor(s, 1);
    float lse = __logf(s) + m;

    if (par == 0) {
        float4* o = (float4*)out + (size_t)i * 10 + sub * 5;
#pragma unroll
        for (int r = 0; r < 5; ++r) {
            o[r] = make_float4(l[r].x - lse, l[r].y - lse, l[r].z - lse, l[r].w - lse);
        }
    }
}

// ================= launch =================

extern "C" void kernel_launch(void* const* d_in, const int* in_sizes, int n_in,
                              void* d_out, int out_size, void* d_ws, size_t ws_size,
                              hipStream_t stream) {
    const float* x   = (const float*)d_in[0];
    const int*   ei  = (const int*)d_in[1];
    const float* W   = (const float*)d_in[2];
    const float* b   = (const float*)d_in[3];
    float*       out = (float*)d_out;

    const int* esrc = ei;
    const int* edst = ei + N_EDGES;

    // workspace layout
    int*   deg   = (int*)d_ws;                         // NPAD ints
    uint4* wfrag = (uint4*)(deg + NPAD);               // 768 uint4 (3072 ints)
    int*   ell   = (int*)(deg + NPAD + 3072);          // MAXW planes x N_NODES ints
    unsigned short* y0 = (unsigned short*)(ell + (size_t)N_NODES * MAXW); // 6.4M shorts
    unsigned short* u1 = y0 + (size_t)N_NODES * USTRIDE;

    const int B = 256;
    const int gG = (16 * N_NODES + B - 1) / B;         // 6250 (16 threads/node)

    k_zero_wconv<<<G_ZERO, B, 0, stream>>>((int4*)deg, W, wfrag);
    k_gemm_ell<<<G_GEMM, B, 0, stream>>>(x, wfrag, y0, esrc, edst, deg, ell);
    k_gather1  <<<gG, B, 0, stream>>>(y0, u1, deg, ell);
    k_gather_out<<<gG, B, 0, stream>>>(u1, out, deg, ell, b);
}

// Round 24
// 83.273 us; speedup vs baseline: 1.0072x; 1.0043x over previous
//
#include <hip/hip_runtime.h>

#define N_NODES   100000
#define N_EDGES   600000
#define D_FEAT    128
#define N_CLASSES 40
#define USTRIDE   64                // bf16 elems/row -> 128 B, one cache line
#define MAXW      40                // ELL width; P(Poisson(6) > 40) ~ 1e-24, guarded

#define NPAD      100352            // N_NODES padded to 1024 multiple
#define N_TILES   (N_NODES / 16)    // 6250 exact
#define G_GEMM    3128                            // 391*8: 2 tiles/block, XCD-swizzled (covers 6255)
#define EPB       192                             // edges per block (3128*192 >= 600k), 1 slot/thread
#define G_ZERO    (NPAD / 4 / 256 + 1)           // 98 zero blocks + 1 wconv block

typedef __attribute__((ext_vector_type(8))) short bf16x8;
typedef __attribute__((ext_vector_type(4))) float f32x4;

// ---------- bf16 helpers (RTNE) ----------
__device__ __forceinline__ float bf2f(unsigned int h) { return __uint_as_float(h << 16); }
__device__ __forceinline__ unsigned int f2bf(float f) {
    unsigned int u = __float_as_uint(f);
    return (u + 0x7FFFu + ((u >> 16) & 1u)) >> 16;
}
__device__ __forceinline__ float4 up4(uint2 v) {
    return make_float4(bf2f(v.x & 0xFFFFu), bf2f(v.x >> 16),
                       bf2f(v.y & 0xFFFFu), bf2f(v.y >> 16));
}
__device__ __forceinline__ uint2 pk4(float4 f) {
    uint2 r;
    r.x = f2bf(f.x) | (f2bf(f.y) << 16);
    r.y = f2bf(f.z) | (f2bf(f.w) << 16);
    return r;
}

// ================= zero deg + precompute W MFMA fragments =================

__global__ void k_zero_wconv(int4* __restrict__ deg4, const float* __restrict__ W,
                             uint4* __restrict__ wfrag) {
    int t = threadIdx.x;
    if (blockIdx.x < G_ZERO - 1) {
        int i = blockIdx.x * 256 + t;
        if (i < NPAD / 4) deg4[i] = make_int4(0, 0, 0, 0);
        return;
    }
    for (int idx = t; idx < 768; idx += 256) {
        int lane = idx & 63;
        int kc   = (idx >> 6) & 3;
        int ct   = idx >> 8;
        int r16  = lane & 15;
        int g    = lane >> 4;
        int j    = ct * 16 + r16;
        uint4 o = make_uint4(0u, 0u, 0u, 0u);
        if (j < N_CLASSES) {
            const float* wr = W + (size_t)j * D_FEAT + kc * 32 + g * 8;
            float4 w0 = *(const float4*)wr;
            float4 w1 = *(const float4*)(wr + 4);
            o.x = f2bf(w0.x) | (f2bf(w0.y) << 16);
            o.y = f2bf(w0.z) | (f2bf(w0.w) << 16);
            o.z = f2bf(w1.x) | (f2bf(w1.y) << 16);
            o.w = f2bf(w1.z) | (f2bf(w1.w) << 16);
        }
        wfrag[idx] = o;
    }
}

// ========== fused: K-split MFMA gemm + count + ELL fill ==========
// Two waves per tile: wave h computes kc in {2h, 2h+1} (half the x chunk
// = 4KB in flight, half the stall), partials combined via LDS (layout
// lacc[12][128]: consecutive lanes -> consecutive banks, conflict-free)
// + one barrier; h=0 does the epilogue. 12500 waves (2x r23) for latency
// hiding. Edge work: 1 slot/thread, staged before the MFMA chain.

__global__ __launch_bounds__(256) void k_gemm_ell(const float* __restrict__ x,
                                                  const uint4* __restrict__ wfrag,
                                                  unsigned short* __restrict__ y0,
                                                  const int* __restrict__ esrc,
                                                  const int* __restrict__ edst,
                                                  int* __restrict__ deg,
                                                  int* __restrict__ ell) {
    int t = threadIdx.x;
    int wid  = t >> 6;
    int pair = wid >> 1;           // tile slot within block (0..1)
    int h    = wid & 1;            // k-half (kc = 2h, 2h+1)
    int lane = t & 63;
    int tile = (blockIdx.x & 7) + 8 * ((blockIdx.x >> 3) * 2 + pair);
    bool valid = tile < N_TILES;

    int r16 = lane & 15;           // node-in-tile (B-operand col / D col)
    int g   = lane >> 4;           // k-group (8 elems each)
    int node = tile * 16 + r16;

    __shared__ float lacc[12][128];    // 6 KB: [acc elem][pair*64+lane]

    // --- stage 1: edge load (1 slot/thread) ---
    int e0 = blockIdx.x * EPB + t;
    bool v0 = (t < EPB) && (e0 < N_EDGES);
    int d0 = 0, src0 = 0;
    if (v0) { d0 = edst[e0]; src0 = esrc[e0]; }

    // --- stage 2: gemm loads (6 wfrag + 4 x, b128 each) ---
    uint4 wq[6];
    float4 xv[4];
    if (valid) {
#pragma unroll
        for (int ct = 0; ct < 3; ++ct)
#pragma unroll
            for (int k2 = 0; k2 < 2; ++k2)
                wq[ct * 2 + k2] = wfrag[(ct * 4 + 2 * h + k2) * 64 + lane];
        const float4* xp = (const float4*)(x + (size_t)node * D_FEAT);
#pragma unroll
        for (int k2 = 0; k2 < 2; ++k2) {
            int kc = 2 * h + k2;
            xv[k2 * 2]     = xp[kc * 8 + g * 2];
            xv[k2 * 2 + 1] = xp[kc * 8 + g * 2 + 1];
        }
    }

    // --- stage 3: atomic issues (return consumed in stage 6) ---
    int o0 = 0;
    if (v0) o0 = atomicAdd(&deg[d0], 1);

    // --- stage 4: convert x to bf16 fragments ---
    bf16x8 afrag[2];
    if (valid) {
#pragma unroll
        for (int k2 = 0; k2 < 2; ++k2) {
            union { bf16x8 v; unsigned int u[4]; } a;
            a.u[0] = f2bf(xv[k2 * 2].x) | (f2bf(xv[k2 * 2].y) << 16);
            a.u[1] = f2bf(xv[k2 * 2].z) | (f2bf(xv[k2 * 2].w) << 16);
            a.u[2] = f2bf(xv[k2 * 2 + 1].x) | (f2bf(xv[k2 * 2 + 1].y) << 16);
            a.u[3] = f2bf(xv[k2 * 2 + 1].z) | (f2bf(xv[k2 * 2 + 1].w) << 16);
            afrag[k2] = a.v;
        }
    }

    // --- stage 5: MFMA chain (6 per wave; atomic latency hides here) ---
    f32x4 z = {0.f, 0.f, 0.f, 0.f};
    f32x4 acc0 = z, acc1 = z, acc2 = z;
    if (valid) {
#pragma unroll
        for (int k2 = 0; k2 < 2; ++k2) {
            union { uint4 u4; bf16x8 v; } b0, b1, b2;
            b0.u4 = wq[k2];  b1.u4 = wq[2 + k2];  b2.u4 = wq[4 + k2];
            acc0 = __builtin_amdgcn_mfma_f32_16x16x32_bf16(b0.v, afrag[k2], acc0, 0, 0, 0);
            acc1 = __builtin_amdgcn_mfma_f32_16x16x32_bf16(b1.v, afrag[k2], acc1, 0, 0, 0);
            acc2 = __builtin_amdgcn_mfma_f32_16x16x32_bf16(b2.v, afrag[k2], acc2, 0, 0, 0);
        }
    }

    // --- stage 6: ELL store (transposed planes; first consumer of o0) ---
    if (v0 && o0 < MAXW) ell[(size_t)o0 * N_NODES + d0] = src0;

    // --- stage 7: cross-wave K combine ---
    int li = pair * 64 + lane;
    if (valid && h == 1) {
#pragma unroll
        for (int j = 0; j < 4; ++j) {
            lacc[j][li]     = acc0[j];
            lacc[4 + j][li] = acc1[j];
            lacc[8 + j][li] = acc2[j];
        }
    }
    __syncthreads();
    if (!valid || h == 1) return;
#pragma unroll
    for (int j = 0; j < 4; ++j) {
        acc0[j] += lacc[j][li];
        acc1[j] += lacc[4 + j][li];
        acc2[j] += lacc[8 + j][li];
    }

    // --- epilogue (h=0 wave): unscaled y0; full-line coverage pad stores ---
    unsigned short* orow = y0 + (size_t)node * USTRIDE;
    uint2 s0, s1;
    s0.x = f2bf(acc0[0]) | (f2bf(acc0[1]) << 16);
    s0.y = f2bf(acc0[2]) | (f2bf(acc0[3]) << 16);
    *(uint2*)(orow + g * 4) = s0;
    s1.x = f2bf(acc1[0]) | (f2bf(acc1[1]) << 16);
    s1.y = f2bf(acc1[2]) | (f2bf(acc1[3]) << 16);
    *(uint2*)(orow + 16 + g * 4) = s1;
    if (g < 2) {
        uint2 s2;
        s2.x = f2bf(acc2[0]) | (f2bf(acc2[1]) << 16);
        s2.y = f2bf(acc2[2]) | (f2bf(acc2[3]) << 16);
        *(uint2*)(orow + 32 + g * 4) = s2;
    } else {
        *(uint4*)(orow + 32 + g * 8) = make_uint4(0u, 0u, 0u, 0u);  // shorts 48..63
    }
    if (g == 1) *(uint4*)(orow + 40) = make_uint4(0u, 0u, 0u, 0u);  // shorts 40..47
}

// ================= round 1: u1[d] = dinv_d^2 * (dinv_d*y0[d] + sum dinv_s*y0[s]) =====

__global__ __launch_bounds__(256) void k_gather1(const unsigned short* __restrict__ y0,
                                                 unsigned short* __restrict__ u1,
                                                 const int* __restrict__ deg,
                                                 const int* __restrict__ ell) {
    int t = blockIdx.x * blockDim.x + threadIdx.x;
    int i = t >> 4;
    if (i >= N_NODES) return;
    int sub = t & 1;
    int par = (t >> 1) & 7;
    const uint2* yb = (const uint2*)y0;

    int degi = deg[i];
    float di = rsqrtf((float)(degi + 1));

    float4 a[5];
    if (par == 0) {
        const uint2* self = yb + (size_t)i * 16 + sub * 5;
#pragma unroll
        for (int r = 0; r < 5; ++r) {
            float4 v = up4(self[r]);
            a[r] = make_float4(v.x * di, v.y * di, v.z * di, v.w * di);
        }
    } else {
#pragma unroll
        for (int r = 0; r < 5; ++r) a[r] = make_float4(0.f, 0.f, 0.f, 0.f);
    }

    int nd = degi < MAXW ? degi : MAXW;
    for (int k = par; k < nd; k += 8) {
        int s = ell[(size_t)k * N_NODES + i];
        float ds = rsqrtf((float)(deg[s] + 1));
        const uint2* p = yb + (size_t)s * 16 + sub * 5;
        uint2 w[5];
#pragma unroll
        for (int r = 0; r < 5; ++r) w[r] = p[r];
#pragma unroll
        for (int r = 0; r < 5; ++r) {
            float4 v = up4(w[r]);
            a[r].x += v.x * ds; a[r].y += v.y * ds;
            a[r].z += v.z * ds; a[r].w += v.w * ds;
        }
    }

#pragma unroll
    for (int d = 2; d <= 8; d <<= 1) {
#pragma unroll
        for (int r = 0; r < 5; ++r) {
            a[r].x += __shfl_xor(a[r].x, d); a[r].y += __shfl_xor(a[r].y, d);
            a[r].z += __shfl_xor(a[r].z, d); a[r].w += __shfl_xor(a[r].w, d);
        }
    }

    unsigned short* orow = u1 + (size_t)i * USTRIDE;
    if (par == 0) {
        float s2 = di * di;
        uint2* o = (uint2*)orow + sub * 5;
#pragma unroll
        for (int r = 0; r < 5; ++r) {
            o[r] = pk4(make_float4(a[r].x * s2, a[r].y * s2, a[r].z * s2, a[r].w * s2));
        }
    } else if (par == 1) {
        *(uint4*)(orow + 40 + sub * 8) = make_uint4(0u, 0u, 0u, 0u);  // shorts 40..55
    } else if (par == 2 && sub == 0) {
        *(uint4*)(orow + 56) = make_uint4(0u, 0u, 0u, 0u);            // shorts 56..63
    }
}

// ======= round 2 + head: logits = dinv_d*(u1[d] + sum u1[s]) + b, log_softmax =======

__global__ __launch_bounds__(256) void k_gather_out(const unsigned short* __restrict__ u1,
                                                    float* __restrict__ out,
                                                    const int* __restrict__ deg,
                                                    const int* __restrict__ ell,
                                                    const float* __restrict__ bias) {
    int t = blockIdx.x * blockDim.x + threadIdx.x;
    int i = t >> 4;
    if (i >= N_NODES) return;
    int sub = t & 1;
    int par = (t >> 1) & 7;
    const uint2* yb = (const uint2*)u1;

    int degi = deg[i];
    float di = rsqrtf((float)(degi + 1));

    float4 a[5];
    if (par == 0) {
        const uint2* self = yb + (size_t)i * 16 + sub * 5;
#pragma unroll
        for (int r = 0; r < 5; ++r) a[r] = up4(self[r]);
    } else {
#pragma unroll
        for (int r = 0; r < 5; ++r) a[r] = make_float4(0.f, 0.f, 0.f, 0.f);
    }

    int nd = degi < MAXW ? degi : MAXW;
    for (int k = par; k < nd; k += 8) {
        int s = ell[(size_t)k * N_NODES + i];
        const uint2* p = yb + (size_t)s * 16 + sub * 5;
        uint2 w[5];
#pragma unroll
        for (int r = 0; r < 5; ++r) w[r] = p[r];
#pragma unroll
        for (int r = 0; r < 5; ++r) {
            float4 v = up4(w[r]);
            a[r].x += v.x; a[r].y += v.y; a[r].z += v.z; a[r].w += v.w;
        }
    }

#pragma unroll
    for (int d = 2; d <= 8; d <<= 1) {
#pragma unroll
        for (int r = 0; r < 5; ++r) {
            a[r].x += __shfl_xor(a[r].x, d); a[r].y += __shfl_xor(a[r].y, d);
            a[r].z += __shfl_xor(a[r].z, d); a[r].w += __shfl_xor(a[r].w, d);
        }
    }

    const float4* b4 = (const float4*)bias + sub * 5;
    float4 l[5];
    float m = -INFINITY;
#pragma unroll
    for (int r = 0; r < 5; ++r) {
        float4 b = b4[r];
        l[r].x = a[r].x * di + b.x;
        l[r].y = a[r].y * di + b.y;
        l[r].z = a[r].z * di + b.z;
        l[r].w = a[r].w * di + b.w;
        m = fmaxf(m, fmaxf(fmaxf(l[r].x, l[r].y), fmaxf(l[r].z, l[r].w)));
    }
    m = fmaxf(m, __shfl_xor(m, 1));     // combine class halves (bit 0)
    float s = 0.f;
#pragma unroll
    for (int r = 0; r < 5; ++r) {
        s += __expf(l[r].x - m) + __expf(l[r].y - m)
           + __expf(l[r].z - m) + __expf(l[r].w - m);
    }
    s += __shfl_xor(s, 1);
    float lse = __logf(s) + m;

    if (par == 0) {
        float4* o = (float4*)out + (size_t)i * 10 + sub * 5;
#pragma unroll
        for (int r = 0; r < 5; ++r) {
            o[r] = make_float4(l[r].x - lse, l[r].y - lse, l[r].z - lse, l[r].w - lse);
        }
    }
}

// ================= launch =================

extern "C" void kernel_launch(void* const* d_in, const int* in_sizes, int n_in,
                              void* d_out, int out_size, void* d_ws, size_t ws_size,
                              hipStream_t stream) {
    const float* x   = (const float*)d_in[0];
    const int*   ei  = (const int*)d_in[1];
    const float* W   = (const float*)d_in[2];
    const float* b   = (const float*)d_in[3];
    float*       out = (float*)d_out;

    const int* esrc = ei;
    const int* edst = ei + N_EDGES;

    // workspace layout
    int*   deg   = (int*)d_ws;                         // NPAD ints
    uint4* wfrag = (uint4*)(deg + NPAD);               // 768 uint4 (3072 ints)
    int*   ell   = (int*)(deg + NPAD + 3072);          // MAXW planes x N_NODES ints
    unsigned short* y0 = (unsigned short*)(ell + (size_t)N_NODES * MAXW); // 6.4M shorts
    unsigned short* u1 = y0 + (size_t)N_NODES * USTRIDE;

    const int B = 256;
    const int gG = (16 * N_NODES + B - 1) / B;         // 6250 (16 threads/node)

    k_zero_wconv<<<G_ZERO, B, 0, stream>>>((int4*)deg, W, wfrag);
    k_gemm_ell<<<G_GEMM, B, 0, stream>>>(x, wfrag, y0, esrc, edst, deg, ell);
    k_gather1  <<<gG, B, 0, stream>>>(y0, u1, deg, ell);
    k_gather_out<<<gG, B, 0, stream>>>(u1, out, deg, ell, b);
}